// Round 8
// baseline (188.897 us; speedup 1.0000x reference)
//
#include <hip/hip_runtime.h>
#include <hip/hip_bf16.h>
#include <stdint.h>

#define B_DIM   4096
#define IN_DIM  4096
#define OUT_DIM 4096
#define K_SEL   128

typedef unsigned short u16;
typedef __bf16 bf16x8 __attribute__((ext_vector_type(8)));
typedef float  f32x4  __attribute__((ext_vector_type(4)));

static __device__ __forceinline__ u16 f2bf(float f) {
    uint32_t u = __builtin_bit_cast(uint32_t, f);
    uint32_t r = (u + 0x7fffu + ((u >> 16) & 1u)) >> 16;
    return (u16)r;
}

// ---------------------------------------------------------------------------
// K1: column sums of W (fp64 partials over 8-row chunks) + W -> bf16.
// 2048 blocks; float4 loads. part = [512][4096] doubles (16MB) in d_out.
// ---------------------------------------------------------------------------
__global__ __launch_bounds__(256) void colsum_conv(const float* __restrict__ W,
                                                   double* __restrict__ part,
                                                   u16* __restrict__ Wb) {
    int cb = blockIdx.x & 3;
    int rb = blockIdx.x >> 2;          // 0..511
    int c4 = cb * 256 + threadIdx.x;   // float4 index within a row
    int row0 = rb * 8;
    double s0 = 0.0, s1 = 0.0, s2 = 0.0, s3 = 0.0;
    for (int r = 0; r < 8; ++r) {
        const float4 v = ((const float4*)(W + (size_t)(row0 + r) * IN_DIM))[c4];
        s0 += (double)v.x; s1 += (double)v.y; s2 += (double)v.z; s3 += (double)v.w;
        ushort4 o;
        o.x = f2bf(v.x); o.y = f2bf(v.y); o.z = f2bf(v.z); o.w = f2bf(v.w);
        ((ushort4*)(Wb + (size_t)(row0 + r) * IN_DIM))[c4] = o;
    }
    double4 d; d.x = s0; d.y = s1; d.z = s2; d.w = s3;
    ((double4*)(part + (size_t)rb * IN_DIM))[c4] = d;
}

// 256 blocks x 256 threads: block handles 16 cols; 16 row-groups of 32.
__global__ __launch_bounds__(256) void colsum_final(const double* __restrict__ part,
                                                    float* __restrict__ cs) {
    __shared__ double red[256];
    const int t = threadIdx.x;
    const int c = blockIdx.x * 16 + (t & 15);
    const int g = t >> 4;              // 0..15
    double s = 0.0;
    for (int r = 0; r < 32; ++r) s += part[(size_t)(g * 32 + r) * IN_DIM + c];
    red[t] = s;
    __syncthreads();
    for (int off = 128; off >= 16; off >>= 1) {
        if (t < off) red[t] += red[t + off];
        __syncthreads();
    }
    if (t < 16) cs[blockIdx.x * 16 + t] = (float)red[t];
}

// ---------------------------------------------------------------------------
// K3: per-row top-128 of |x*colsum| via 4-pass radix select, exact ties
// (lowest index first), write masked x as bf16. One 256-thread block per row.
// ---------------------------------------------------------------------------
__global__ __launch_bounds__(256) void topk_mask(const float* __restrict__ x,
                                                 const float* __restrict__ cs,
                                                 u16* __restrict__ xz) {
    __shared__ uint32_t hist[256];
    __shared__ uint32_t suf[256];
    __shared__ uint32_t s_scan[256];
    __shared__ uint32_t s_prefix, s_krem;

    const int b = blockIdx.x, t = threadIdx.x;
    const float4* xrow = (const float4*)(x + (size_t)b * IN_DIM);
    const float4* csv  = (const float4*)cs;

    float    xr[16];
    uint32_t ul[16];
#pragma unroll
    for (int q = 0; q < 4; ++q) {
        float4 xv = xrow[t * 4 + q];
        float4 cv = csv[t * 4 + q];
        xr[q*4+0] = xv.x; xr[q*4+1] = xv.y; xr[q*4+2] = xv.z; xr[q*4+3] = xv.w;
        ul[q*4+0] = __builtin_bit_cast(uint32_t, xv.x * cv.x) & 0x7fffffffu;
        ul[q*4+1] = __builtin_bit_cast(uint32_t, xv.y * cv.y) & 0x7fffffffu;
        ul[q*4+2] = __builtin_bit_cast(uint32_t, xv.z * cv.z) & 0x7fffffffu;
        ul[q*4+3] = __builtin_bit_cast(uint32_t, xv.w * cv.w) & 0x7fffffffu;
    }
    if (t == 0) { s_prefix = 0u; s_krem = K_SEL; }
    __syncthreads();

#pragma unroll
    for (int p = 3; p >= 0; --p) {
        const int sh = p * 8;
        const uint32_t hi_mask = (p == 3) ? 0u : (0xFFFFFFFFu << (sh + 8));
        const uint32_t prefix = s_prefix;
        const uint32_t krem   = s_krem;
        hist[t] = 0u;
        __syncthreads();
#pragma unroll
        for (int j = 0; j < 16; ++j) {
            uint32_t u = ul[j];
            if ((u & hi_mask) == (prefix & hi_mask))
                atomicAdd(&hist[(u >> sh) & 255u], 1u);
        }
        __syncthreads();
        uint32_t mine = hist[t];
        suf[t] = mine;
        __syncthreads();
#pragma unroll
        for (int off = 1; off < 256; off <<= 1) {
            uint32_t other = (t + off < 256) ? suf[t + off] : 0u;
            __syncthreads();
            mine += other;
            suf[t] = mine;
            __syncthreads();
        }
        uint32_t mysuf   = suf[t];
        uint32_t nextsuf = (t < 255) ? suf[t + 1] : 0u;
        if (mysuf >= krem && (t == 255 || nextsuf < krem)) {
            s_prefix = prefix | ((uint32_t)t << sh);
            s_krem   = krem - nextsuf;
        }
        __syncthreads();
    }
    const uint32_t T       = s_prefix;
    const uint32_t need_eq = s_krem;

    int cnt = 0;
#pragma unroll
    for (int j = 0; j < 16; ++j) cnt += (ul[j] == T) ? 1 : 0;
    s_scan[t] = (uint32_t)cnt;
    __syncthreads();
    uint32_t inc = (uint32_t)cnt;
#pragma unroll
    for (int off = 1; off < 256; off <<= 1) {
        uint32_t other = (t >= off) ? s_scan[t - off] : 0u;
        __syncthreads();
        inc += other;
        s_scan[t] = inc;
        __syncthreads();
    }
    const int base = (int)(inc - (uint32_t)cnt);

    union { u16 us[16]; uint4 v[2]; } ob;
    int eqseen = 0;
#pragma unroll
    for (int j = 0; j < 16; ++j) {
        uint32_t u = ul[j];
        bool drop = (u > T);
        if (u == T) {
            if (base + eqseen < (int)need_eq) drop = true;
            ++eqseen;
        }
        ob.us[j] = drop ? (u16)0 : f2bf(xr[j]);
    }
    uint4* dst = (uint4*)(xz + (size_t)b * IN_DIM + t * 16);
    dst[0] = ob.v[0];
    dst[1] = ob.v[1];
}

// ---------------------------------------------------------------------------
// K4: bf16 GEMM C = A @ B^T, 256x256 tile, BK=64, 8 waves (2Mx4N).
// Pipelined frags, spread counted staging, NO in-loop lgkmcnt(0):
//   WAR safety = every ds_read is consumed by an MFMA (compiler's counted
//   lgkm wait) in a phase STRICTLY BEFORE the overwriting stage, with a
//   barrier between. Waves signal barriers with reads still in flight.
//   MFMA phases P0=(qm0,ks0) P1=(qm0,ks1) P2=(qm1,ks0) P3=(qm1,ks1), 16
//   independent MFMAs each, consuming frags read in the PREVIOUS phase.
//   Reads: P0: a0k1+bk1 | P1: a1k0+a1k1 | P2: none | P3: a0k0+bk0 of
//   tile k+1 from bufN (after the publish barrier).
// Stages (16KB units): P0: S4(k+1)=A-r1->bufN | P1: none |
//   P2: S1(k+2)=A-r0 + S2(k+2)=B-r0 ->bufC, publish vmcnt(4) |
//   P3: S3(k+2)=B-r1 ->bufC.
// WAR ledger (read -> consuming MFMA -> barrier -> stage):
//   S4@P0(k): A-r1 buf(k-1) read P1(k-1), consumed P2/P3(k-1), bar P3-end ok
//   S1@P2(k): A-r0 bufC read P0(k) c1, consumed P1(k), bar P1-end ok
//   S2@P2(k): B-r0 bufC read <=P0(k), consumed <=P1(k), bar P1-end ok
//   S3@P3(k): B-r1 bufC same, one phase later ok
// RAW: publish@P2(k) vmcnt(4) keeps exactly {S1,S2(k+2)}, drains S4(k+1)
//   and older => all 4 regions of tile k+1 complete; first read P3(k).
// vmcnt(0) for k>=NT-2 (tail units not issued). T2 swizzle, T5 setprio.
// ---------------------------------------------------------------------------
#define NT 64

__global__ __launch_bounds__(512, 2) void gemm_pl(const u16* __restrict__ A,
                                                  const u16* __restrict__ Bm,
                                                  float* __restrict__ C) {
    __shared__ u16 lds_[65536];   // 128 KB

    const int bid = blockIdx.x;
    const int swz = (bid & 7) * 32 + (bid >> 3);   // 256 blocks, 8 XCDs
    const int m0 = (swz >> 4) * 256, n0 = (swz & 15) * 256;

    const int t = threadIdx.x;
    const int l = t & 63;
    const int lr = l & 15, lk = l >> 4;
    const int w = t >> 6;
    const int wm = w >> 2, wn = w & 3;

    const int cswz = ((t & 7) ^ ((t >> 3) & 7)) * 8;   // staging src col (elems)
    const int c0   = (lk ^ (lr & 7)) * 8;              // swizzled col, ks=0
    const int c1   = c0 ^ 32;                          // ks=1

    f32x4 acc[8][4];
#pragma unroll
    for (int i = 0; i < 8; ++i)
#pragma unroll
        for (int j = 0; j < 4; ++j) acc[i][j] = f32x4{0.f, 0.f, 0.f, 0.f};

#define GLOAD(g, off_bytes)                                                     \
    __builtin_amdgcn_global_load_lds(                                           \
        (const __attribute__((address_space(1))) void*)(g),                     \
        (__attribute__((address_space(3))) void*)(((char*)lds_) + (off_bytes)), \
        16, 0, 0)

    // A region r: rows {g*128 + r*64 .. +64} for g=0,1 -> 16KB
    auto stA = [&](int kb, int r, int kt) {
#pragma unroll
        for (int g = 0; g < 2; ++g)
            GLOAD(A + (size_t)(m0 + g * 128 + r * 64 + (t >> 3)) * IN_DIM + kt + cswz,
                  kb * 65536 + r * 16384 + g * 8192 + t * 16);
    };
    // B region r: rows {r*128 + g*64 .. +64} for g=0,1 -> 16KB
    auto stB = [&](int kb, int r, int kt) {
#pragma unroll
        for (int g = 0; g < 2; ++g)
            GLOAD(Bm + (size_t)(n0 + r * 128 + g * 64 + (t >> 3)) * IN_DIM + kt + cswz,
                  kb * 65536 + 32768 + r * 16384 + g * 8192 + t * 16);
    };

    // frag reads (elem offsets): A(qm,mi): bufo + qm*8192 + wm*4096 + lr*64
    //  + mi*1024 + c ; B(ni): bufo + 16384 + (wn>>1)*8192 + (wn&1)*4096
    //  + lr*64 + ni*1024 + c
    auto rdA = [&](bf16x8 (&dst)[4], int bufo, int qm, int c) {
#pragma unroll
        for (int mi = 0; mi < 4; ++mi)
            dst[mi] = *(const bf16x8*)&lds_[bufo + qm * 8192 + wm * 4096 + lr * 64 + mi * 1024 + c];
    };
    auto rdB = [&](bf16x8 (&dst)[4], int bufo, int c) {
#pragma unroll
        for (int ni = 0; ni < 4; ++ni)
            dst[ni] = *(const bf16x8*)&lds_[bufo + 16384 + (wn >> 1) * 8192 + (wn & 1) * 4096 + lr * 64 + ni * 1024 + c];
    };
    auto mm = [&](int base, bf16x8 (&Aa)[4], bf16x8 (&Bb)[4]) {
        __builtin_amdgcn_s_setprio(1);
#pragma unroll
        for (int mi = 0; mi < 4; ++mi)
#pragma unroll
            for (int ni = 0; ni < 4; ++ni)
                acc[base + mi][ni] = __builtin_amdgcn_mfma_f32_16x16x32_bf16(
                    Aa[mi], Bb[ni], acc[base + mi][ni], 0, 0, 0);
        __builtin_amdgcn_s_setprio(0);
        __builtin_amdgcn_sched_barrier(0);
    };

    bf16x8 a0k0[4], a0k1[4], a1k0[4], a1k1[4], bk0[4], bk1[4];

    // prologue: tile0 complete + S1,S2,S3(1); vmcnt(6) leaves exactly those 6;
    // publish tile0; pre-read P0's frags.
    stA(0, 0, 0); stA(0, 1, 0); stB(0, 0, 0); stB(0, 1, 0);
    stA(1, 0, 64); stB(1, 0, 64); stB(1, 1, 64);
    asm volatile("s_waitcnt vmcnt(6)" ::: "memory");
    __builtin_amdgcn_s_barrier();
    asm volatile("" ::: "memory");
    rdA(a0k0, 0, 0, c0);
    rdB(bk0, 0, c0);

    for (int k = 0; k < NT; ++k) {
        const int bufo = (k & 1) * 32768;               // elem offset
        const int bufno = bufo ^ 32768;
        const int kbC = k & 1, kbN = kbC ^ 1;
        const int kt1 = (k + 1) * 64, kt2 = (k + 2) * 64;

        // ---- P0 (qm0,ks0): reads a0k1,bk1(k); stage S4(k+1)=A-r1 -> bufN ----
        rdA(a0k1, bufo, 0, c1);
        rdB(bk1, bufo, c1);
        if (k < NT - 1) stA(kbN, 1, kt1);
        mm(0, a0k0, bk0);
        asm volatile("" ::: "memory");
        __builtin_amdgcn_s_barrier();
        asm volatile("" ::: "memory");

        // ---- P1 (qm0,ks1): reads a1k0,a1k1(k); no stage ----
        rdA(a1k0, bufo, 1, c0);
        rdA(a1k1, bufo, 1, c1);
        mm(0, a0k1, bk1);
        asm volatile("" ::: "memory");
        __builtin_amdgcn_s_barrier();
        asm volatile("" ::: "memory");

        // ---- P2 (qm1,ks0): no reads; stage S1(k+2)=A-r0 + S2(k+2)=B-r0;
        //      publish tile k+1 with counted vmcnt ----
        if (k < NT - 2) { stA(kbC, 0, kt2); stB(kbC, 0, kt2); }
        mm(4, a1k0, bk0);
        if (k < NT - 2) {
            asm volatile("s_waitcnt vmcnt(4)" ::: "memory");
        } else {
            asm volatile("s_waitcnt vmcnt(0)" ::: "memory");
        }
        __builtin_amdgcn_s_barrier();
        asm volatile("" ::: "memory");

        // ---- P3 (qm1,ks1): reads a0k0,bk0(k+1) from bufN; stage S3(k+2) ----
        if (k < NT - 1) {
            rdA(a0k0, bufno, 0, c0);
            rdB(bk0, bufno, c0);
        }
        if (k < NT - 2) stB(kbC, 1, kt2);
        mm(4, a1k1, bk1);
        asm volatile("" ::: "memory");
        __builtin_amdgcn_s_barrier();
        asm volatile("" ::: "memory");
    }
#undef GLOAD

    // epilogue: C/D layout col = lane&15, row = (lane>>4)*4 + r
#pragma unroll
    for (int gmi = 0; gmi < 8; ++gmi)
#pragma unroll
        for (int ni = 0; ni < 4; ++ni)
#pragma unroll
            for (int r = 0; r < 4; ++r) {
                int row = m0 + wm * 128 + (gmi >> 2) * 64 + (gmi & 3) * 16 + lk * 4 + r;
                int col = n0 + wn * 64 + ni * 16 + lr;
                C[(size_t)row * OUT_DIM + col] = acc[gmi][ni][r];
            }
}

// ---------------------------------------------------------------------------
extern "C" void kernel_launch(void* const* d_in, const int* in_sizes, int n_in,
                              void* d_out, int out_size, void* d_ws, size_t ws_size,
                              hipStream_t stream) {
    const float* x = (const float*)d_in[0];
    const float* W = (const float*)d_in[1];
    float* out = (float*)d_out;

    char* ws = (char*)d_ws;
    u16*    Wb   = (u16*)ws;                                   // 32 MB bf16 W
    u16*    xz   = (u16*)(ws + (size_t)32 * 1024 * 1024);      // 32 MB bf16 masked x
    float*  cs   = (float*)(ws + (size_t)64 * 1024 * 1024);    // 16 KB colsum
    double* part = (double*)d_out;  // 16 MB partials, consumed before gemm writes

    colsum_conv<<<2048, 256, 0, stream>>>(W, part, Wb);
    colsum_final<<<256, 256, 0, stream>>>(part, cs);
    topk_mask<<<4096, 256, 0, stream>>>(x, cs, xz);
    gemm_pl<<<256, 512, 0, stream>>>(xz, Wb, out);
}

// Round 9
// 187.746 us; speedup vs baseline: 1.0061x; 1.0061x over previous
//
#include <hip/hip_runtime.h>
#include <hip/hip_bf16.h>
#include <stdint.h>

#define B_DIM   4096
#define IN_DIM  4096
#define OUT_DIM 4096
#define K_SEL   128

typedef unsigned short u16;
typedef __bf16 bf16x8 __attribute__((ext_vector_type(8)));
typedef float  f32x4  __attribute__((ext_vector_type(4)));

static __device__ __forceinline__ u16 f2bf(float f) {
    uint32_t u = __builtin_bit_cast(uint32_t, f);
    uint32_t r = (u + 0x7fffu + ((u >> 16) & 1u)) >> 16;
    return (u16)r;
}

// ---------------------------------------------------------------------------
// K1: column sums of W (fp64 partials over 8-row chunks) + W -> bf16.
// ---------------------------------------------------------------------------
__global__ __launch_bounds__(256) void colsum_conv(const float* __restrict__ W,
                                                   double* __restrict__ part,
                                                   u16* __restrict__ Wb) {
    int cb = blockIdx.x & 3;
    int rb = blockIdx.x >> 2;          // 0..511
    int c4 = cb * 256 + threadIdx.x;   // float4 index within a row
    int row0 = rb * 8;
    double s0 = 0.0, s1 = 0.0, s2 = 0.0, s3 = 0.0;
    for (int r = 0; r < 8; ++r) {
        const float4 v = ((const float4*)(W + (size_t)(row0 + r) * IN_DIM))[c4];
        s0 += (double)v.x; s1 += (double)v.y; s2 += (double)v.z; s3 += (double)v.w;
        ushort4 o;
        o.x = f2bf(v.x); o.y = f2bf(v.y); o.z = f2bf(v.z); o.w = f2bf(v.w);
        ((ushort4*)(Wb + (size_t)(row0 + r) * IN_DIM))[c4] = o;
    }
    double4 d; d.x = s0; d.y = s1; d.z = s2; d.w = s3;
    ((double4*)(part + (size_t)rb * IN_DIM))[c4] = d;
}

// 256 blocks x 256 threads: block handles 16 cols; 16 row-groups of 32.
__global__ __launch_bounds__(256) void colsum_final(const double* __restrict__ part,
                                                    float* __restrict__ cs) {
    __shared__ double red[256];
    const int t = threadIdx.x;
    const int c = blockIdx.x * 16 + (t & 15);
    const int g = t >> 4;              // 0..15
    double s = 0.0;
    for (int r = 0; r < 32; ++r) s += part[(size_t)(g * 32 + r) * IN_DIM + c];
    red[t] = s;
    __syncthreads();
    for (int off = 128; off >= 16; off >>= 1) {
        if (t < off) red[t] += red[t + off];
        __syncthreads();
    }
    if (t < 16) cs[blockIdx.x * 16 + t] = (float)red[t];
}

// ---------------------------------------------------------------------------
// K3: per-row top-128 of |x*colsum| via 4-pass radix select, exact ties
// (lowest index first), write masked x as bf16. One 256-thread block per row.
// ---------------------------------------------------------------------------
__global__ __launch_bounds__(256) void topk_mask(const float* __restrict__ x,
                                                 const float* __restrict__ cs,
                                                 u16* __restrict__ xz) {
    __shared__ uint32_t hist[256];
    __shared__ uint32_t suf[256];
    __shared__ uint32_t s_scan[256];
    __shared__ uint32_t s_prefix, s_krem;

    const int b = blockIdx.x, t = threadIdx.x;
    const float4* xrow = (const float4*)(x + (size_t)b * IN_DIM);
    const float4* csv  = (const float4*)cs;

    float    xr[16];
    uint32_t ul[16];
#pragma unroll
    for (int q = 0; q < 4; ++q) {
        float4 xv = xrow[t * 4 + q];
        float4 cv = csv[t * 4 + q];
        xr[q*4+0] = xv.x; xr[q*4+1] = xv.y; xr[q*4+2] = xv.z; xr[q*4+3] = xv.w;
        ul[q*4+0] = __builtin_bit_cast(uint32_t, xv.x * cv.x) & 0x7fffffffu;
        ul[q*4+1] = __builtin_bit_cast(uint32_t, xv.y * cv.y) & 0x7fffffffu;
        ul[q*4+2] = __builtin_bit_cast(uint32_t, xv.z * cv.z) & 0x7fffffffu;
        ul[q*4+3] = __builtin_bit_cast(uint32_t, xv.w * cv.w) & 0x7fffffffu;
    }
    if (t == 0) { s_prefix = 0u; s_krem = K_SEL; }
    __syncthreads();

#pragma unroll
    for (int p = 3; p >= 0; --p) {
        const int sh = p * 8;
        const uint32_t hi_mask = (p == 3) ? 0u : (0xFFFFFFFFu << (sh + 8));
        const uint32_t prefix = s_prefix;
        const uint32_t krem   = s_krem;
        hist[t] = 0u;
        __syncthreads();
#pragma unroll
        for (int j = 0; j < 16; ++j) {
            uint32_t u = ul[j];
            if ((u & hi_mask) == (prefix & hi_mask))
                atomicAdd(&hist[(u >> sh) & 255u], 1u);
        }
        __syncthreads();
        uint32_t mine = hist[t];
        suf[t] = mine;
        __syncthreads();
#pragma unroll
        for (int off = 1; off < 256; off <<= 1) {
            uint32_t other = (t + off < 256) ? suf[t + off] : 0u;
            __syncthreads();
            mine += other;
            suf[t] = mine;
            __syncthreads();
        }
        uint32_t mysuf   = suf[t];
        uint32_t nextsuf = (t < 255) ? suf[t + 1] : 0u;
        if (mysuf >= krem && (t == 255 || nextsuf < krem)) {
            s_prefix = prefix | ((uint32_t)t << sh);
            s_krem   = krem - nextsuf;
        }
        __syncthreads();
    }
    const uint32_t T       = s_prefix;
    const uint32_t need_eq = s_krem;

    int cnt = 0;
#pragma unroll
    for (int j = 0; j < 16; ++j) cnt += (ul[j] == T) ? 1 : 0;
    s_scan[t] = (uint32_t)cnt;
    __syncthreads();
    uint32_t inc = (uint32_t)cnt;
#pragma unroll
    for (int off = 1; off < 256; off <<= 1) {
        uint32_t other = (t >= off) ? s_scan[t - off] : 0u;
        __syncthreads();
        inc += other;
        s_scan[t] = inc;
        __syncthreads();
    }
    const int base = (int)(inc - (uint32_t)cnt);

    union { u16 us[16]; uint4 v[2]; } ob;
    int eqseen = 0;
#pragma unroll
    for (int j = 0; j < 16; ++j) {
        uint32_t u = ul[j];
        bool drop = (u > T);
        if (u == T) {
            if (base + eqseen < (int)need_eq) drop = true;
            ++eqseen;
        }
        ob.us[j] = drop ? (u16)0 : f2bf(xr[j]);
    }
    uint4* dst = (uint4*)(xz + (size_t)b * IN_DIM + t * 16);
    dst[0] = ob.v[0];
    dst[1] = ob.v[1];
}

// ---------------------------------------------------------------------------
// K4: bf16 GEMM C = A @ B^T — faithful m201 8-phase port.
// 256x256 tile, BK=64, 8 waves (2Mx4N, per-wave 128x64). LDS per buf:
//   A-h0 @0, A-h1 @16K (h = wm: rows h*128..+128 x 64K)
//   B-h0 @32K, B-h1 @48K (h = wn>>1: n-rows h*128..+128 x 64K)
// Phases per tile = C-quadrants, synchronous (read -> bar -> lgkm0 -> MFMA):
//   P1 (qm0,qn0): read A0(8) + B0(4) [12 -> lgkmcnt(8) hint]
//   P2 (qm1,qn0): read A1(8)            [B0 regs reused]
//   P3 (qm1,qn1): read B1(4)            [A1 regs reused]
//   P4 (qm0,qn1): read none             [A0 regs persist across tile]
// Staging 1 half-tile (16KB = 2 gloads)/phase, 3+ phases before drain:
//   P1: B-h1(T+1)->bufN | P2: A-h0(T+2)->bufC | P3: A-h1(T+2) | P4: B-h0(T+2)
// vmcnt(6) ONLY at P4-end (outstanding = exactly T+2's 3 half-tiles; drains
// B-h1(T+1) and older => tile T+1 resident before P1(T+1)). vmcnt(0) @T=62.
// WAR ledger: each stage target's reads consumed by MFMA (behind lgkmcnt(0))
// in a strictly earlier phase, barrier between:
//   B-h1(T+1)@P1(T): read P3(T-1), consumed P3(T-1) | A-h0(T+2)@P2(T): read
//   P1(T), consumed P1 | A-h1@P3: read P2, consumed P2 | B-h0@P4: read P1.
// T2 XOR-swizzle (0 conflicts), T5 setprio, rule-#18 sched_barrier.
// ---------------------------------------------------------------------------
#define NT 64

__global__ __launch_bounds__(512, 2) void gemm_m2(const u16* __restrict__ A,
                                                  const u16* __restrict__ Bm,
                                                  float* __restrict__ C) {
    __shared__ u16 lds_[65536];   // 128 KB

    const int bid = blockIdx.x;
    const int swz = (bid & 7) * 32 + (bid >> 3);   // 256 blocks, 8 XCDs
    const int m0 = (swz >> 4) * 256, n0 = (swz & 15) * 256;

    const int t = threadIdx.x;
    const int l = t & 63;
    const int lr = l & 15, lk = l >> 4;
    const int w = t >> 6;
    const int wm = w >> 2, wn = w & 3;

    const int cswz = ((t & 7) ^ ((t >> 3) & 7)) * 8;   // staging src col (elems)
    const int c0   = (lk ^ (lr & 7)) * 8;              // swizzled col, ks=0
    const int c1   = c0 ^ 32;                          // ks=1

    f32x4 acc[8][4];
#pragma unroll
    for (int i = 0; i < 8; ++i)
#pragma unroll
        for (int j = 0; j < 4; ++j) acc[i][j] = f32x4{0.f, 0.f, 0.f, 0.f};

#define GLOAD(g, off_bytes)                                                     \
    __builtin_amdgcn_global_load_lds(                                           \
        (const __attribute__((address_space(1))) void*)(g),                     \
        (__attribute__((address_space(3))) void*)(((char*)lds_) + (off_bytes)), \
        16, 0, 0)

    // stage A half h (rows h*128..+128, 16KB = 2 gloads) of K-tile col kt
    auto stA = [&](int kb, int h, int kt) {
#pragma unroll
        for (int g = 0; g < 2; ++g)
            GLOAD(A + (size_t)(m0 + h * 128 + g * 64 + (t >> 3)) * IN_DIM + kt + cswz,
                  kb * 65536 + h * 16384 + g * 8192 + t * 16);
    };
    // stage B half h (n-rows h*128..+128)
    auto stB = [&](int kb, int h, int kt) {
#pragma unroll
        for (int g = 0; g < 2; ++g)
            GLOAD(Bm + (size_t)(n0 + h * 128 + g * 64 + (t >> 3)) * IN_DIM + kt + cswz,
                  kb * 65536 + 32768 + h * 16384 + g * 8192 + t * 16);
    };

    // frag reads (elem offsets). A-h(wm) base: bufo + wm*8192; region row =
    // qm*64 + mi*16 + lr. B-h(wn>>1) base: bufo + 16384 + (wn>>1)*8192;
    // region row = (wn&1)*64 + qn*32 + ni2*16 + lr.
    auto rdA = [&](bf16x8 (&dst)[4][2], int bufo, int qm) {
#pragma unroll
        for (int mi = 0; mi < 4; ++mi) {
            int ro = bufo + wm * 8192 + (qm * 64 + mi * 16 + lr) * 64;
            dst[mi][0] = *(const bf16x8*)&lds_[ro + c0];
            dst[mi][1] = *(const bf16x8*)&lds_[ro + c1];
        }
    };
    auto rdB = [&](bf16x8 (&dst)[2][2], int bufo, int qn) {
#pragma unroll
        for (int n2 = 0; n2 < 2; ++n2) {
            int ro = bufo + 16384 + (wn >> 1) * 8192 + ((wn & 1) * 64 + qn * 32 + n2 * 16 + lr) * 64;
            dst[n2][0] = *(const bf16x8*)&lds_[ro + c0];
            dst[n2][1] = *(const bf16x8*)&lds_[ro + c1];
        }
    };
    auto mm = [&](int mb, int nb, bf16x8 (&Aa)[4][2], bf16x8 (&Bb)[2][2]) {
        __builtin_amdgcn_s_setprio(1);
#pragma unroll
        for (int mi = 0; mi < 4; ++mi)
#pragma unroll
            for (int n2 = 0; n2 < 2; ++n2) {
                acc[mb + mi][nb + n2] = __builtin_amdgcn_mfma_f32_16x16x32_bf16(
                    Aa[mi][0], Bb[n2][0], acc[mb + mi][nb + n2], 0, 0, 0);
                acc[mb + mi][nb + n2] = __builtin_amdgcn_mfma_f32_16x16x32_bf16(
                    Aa[mi][1], Bb[n2][1], acc[mb + mi][nb + n2], 0, 0, 0);
            }
        __builtin_amdgcn_s_setprio(0);
        __builtin_amdgcn_sched_barrier(0);
    };

    bf16x8 A0[4][2], A1[4][2], B0[2][2], B1[2][2];

    // prologue: tile0 (4 halves) + tile1 {A-h0, A-h1, B-h0}; vmcnt(6) leaves
    // exactly tile1's 6 gloads; tile0 resident.
    stA(0, 0, 0);  stA(0, 1, 0);  stB(0, 0, 0);  stB(0, 1, 0);
    stA(1, 0, 64); stA(1, 1, 64); stB(1, 0, 64);
    asm volatile("s_waitcnt vmcnt(6)" ::: "memory");
    __builtin_amdgcn_s_barrier();
    asm volatile("" ::: "memory");

    for (int k = 0; k < NT; ++k) {
        const int bufo = (k & 1) * 32768;               // elem offset
        const int cur = k & 1, nxt = cur ^ 1;
        const int kt1 = (k + 1) * 64, kt2 = (k + 2) * 64;

        // ---- P1 (qm0,qn0): read A0 + B0 (12); stage B-h1(k+1) -> bufN ----
        rdA(A0, bufo, 0);
        rdB(B0, bufo, 0);
        if (k < NT - 1) stB(nxt, 1, kt1);
        asm volatile("s_waitcnt lgkmcnt(8)" ::: "memory");
        __builtin_amdgcn_s_barrier();
        asm volatile("s_waitcnt lgkmcnt(0)" ::: "memory");
        __builtin_amdgcn_sched_barrier(0);
        mm(0, 0, A0, B0);
        asm volatile("" ::: "memory");
        __builtin_amdgcn_s_barrier();
        asm volatile("" ::: "memory");

        // ---- P2 (qm1,qn0): read A1 (8); stage A-h0(k+2) -> bufC ----
        rdA(A1, bufo, 1);
        if (k < NT - 2) stA(cur, 0, kt2);
        asm volatile("" ::: "memory");
        __builtin_amdgcn_s_barrier();
        asm volatile("s_waitcnt lgkmcnt(0)" ::: "memory");
        __builtin_amdgcn_sched_barrier(0);
        mm(4, 0, A1, B0);
        asm volatile("" ::: "memory");
        __builtin_amdgcn_s_barrier();
        asm volatile("" ::: "memory");

        // ---- P3 (qm1,qn1): read B1 (4); stage A-h1(k+2) -> bufC ----
        rdB(B1, bufo, 1);
        if (k < NT - 2) stA(cur, 1, kt2);
        asm volatile("" ::: "memory");
        __builtin_amdgcn_s_barrier();
        asm volatile("s_waitcnt lgkmcnt(0)" ::: "memory");
        __builtin_amdgcn_sched_barrier(0);
        mm(4, 2, A1, B1);
        asm volatile("" ::: "memory");
        __builtin_amdgcn_s_barrier();
        asm volatile("" ::: "memory");

        // ---- P4 (qm0,qn1): no reads; stage B-h0(k+2) -> bufC; vmcnt ----
        if (k < NT - 2) stB(cur, 0, kt2);
        asm volatile("" ::: "memory");
        __builtin_amdgcn_s_barrier();
        asm volatile("" ::: "memory");
        __builtin_amdgcn_sched_barrier(0);
        mm(0, 2, A0, B1);
        if (k < NT - 2) {
            asm volatile("s_waitcnt vmcnt(6)" ::: "memory");
        } else if (k == NT - 2) {
            asm volatile("s_waitcnt vmcnt(0)" ::: "memory");
        }
        __builtin_amdgcn_s_barrier();
        asm volatile("" ::: "memory");
    }
#undef GLOAD

    // epilogue: C/D layout col = lane&15, row = (lane>>4)*4 + r
#pragma unroll
    for (int gmi = 0; gmi < 8; ++gmi)
#pragma unroll
        for (int ni = 0; ni < 4; ++ni)
#pragma unroll
            for (int r = 0; r < 4; ++r) {
                int row = m0 + wm * 128 + (gmi >> 2) * 64 + (gmi & 3) * 16 + lk * 4 + r;
                int col = n0 + wn * 64 + ni * 16 + lr;
                C[(size_t)row * OUT_DIM + col] = acc[gmi][ni][r];
            }
}

// ---------------------------------------------------------------------------
extern "C" void kernel_launch(void* const* d_in, const int* in_sizes, int n_in,
                              void* d_out, int out_size, void* d_ws, size_t ws_size,
                              hipStream_t stream) {
    const float* x = (const float*)d_in[0];
    const float* W = (const float*)d_in[1];
    float* out = (float*)d_out;

    char* ws = (char*)d_ws;
    u16*    Wb   = (u16*)ws;                                   // 32 MB bf16 W
    u16*    xz   = (u16*)(ws + (size_t)32 * 1024 * 1024);      // 32 MB bf16 masked x
    float*  cs   = (float*)(ws + (size_t)64 * 1024 * 1024);    // 16 KB colsum
    double* part = (double*)d_out;  // 16 MB partials, consumed before gemm writes

    colsum_conv<<<2048, 256, 0, stream>>>(W, part, Wb);
    colsum_final<<<256, 256, 0, stream>>>(part, cs);
    topk_mask<<<4096, 256, 0, stream>>>(x, cs, xz);
    gemm_m2<<<256, 512, 0, stream>>>(xz, Wb, out);
}

// Round 10
// 180.624 us; speedup vs baseline: 1.0458x; 1.0394x over previous
//
#include <hip/hip_runtime.h>
#include <hip/hip_bf16.h>
#include <stdint.h>

#define B_DIM   4096
#define IN_DIM  4096
#define OUT_DIM 4096
#define K_SEL   128

typedef unsigned short u16;
typedef __bf16 bf16x8 __attribute__((ext_vector_type(8)));
typedef float  f32x4  __attribute__((ext_vector_type(4)));

static __device__ __forceinline__ u16 f2bf(float f) {
    uint32_t u = __builtin_bit_cast(uint32_t, f);
    uint32_t r = (u + 0x7fffu + ((u >> 16) & 1u)) >> 16;
    return (u16)r;
}

// ---------------------------------------------------------------------------
// K1: column sums of W (fp64 partials over 32-row chunks) + W -> bf16.
// 512 blocks = (4 col-chunks x 128 row-chunks) x 256 threads; float4 loads.
// part = [128][4096] doubles (4MB) in d_out, consumed before gemm writes.
// ---------------------------------------------------------------------------
__global__ __launch_bounds__(256) void colsum_conv(const float* __restrict__ W,
                                                   double* __restrict__ part,
                                                   u16* __restrict__ Wb) {
    int cb = blockIdx.x & 3;
    int rb = blockIdx.x >> 2;          // 0..127
    int c4 = cb * 256 + threadIdx.x;   // float4 index within a row
    int row0 = rb * 32;
    double s0 = 0.0, s1 = 0.0, s2 = 0.0, s3 = 0.0;
    for (int r = 0; r < 32; ++r) {
        const float4 v = ((const float4*)(W + (size_t)(row0 + r) * IN_DIM))[c4];
        s0 += (double)v.x; s1 += (double)v.y; s2 += (double)v.z; s3 += (double)v.w;
        ushort4 o;
        o.x = f2bf(v.x); o.y = f2bf(v.y); o.z = f2bf(v.z); o.w = f2bf(v.w);
        ((ushort4*)(Wb + (size_t)(row0 + r) * IN_DIM))[c4] = o;
    }
    double4 d; d.x = s0; d.y = s1; d.z = s2; d.w = s3;
    ((double4*)(part + (size_t)rb * IN_DIM))[c4] = d;
}

// 256 blocks x 256 threads: block handles 16 cols; 16 row-groups of 8.
__global__ __launch_bounds__(256) void colsum_final(const double* __restrict__ part,
                                                    float* __restrict__ cs) {
    __shared__ double red[256];
    const int t = threadIdx.x;
    const int c = blockIdx.x * 16 + (t & 15);
    const int g = t >> 4;              // 0..15
    double s = 0.0;
    for (int r = 0; r < 8; ++r) s += part[(size_t)(g * 8 + r) * IN_DIM + c];
    red[t] = s;
    __syncthreads();
    for (int off = 128; off >= 16; off >>= 1) {
        if (t < off) red[t] += red[t + off];
        __syncthreads();
    }
    if (t < 16) cs[blockIdx.x * 16 + t] = (float)red[t];
}

// ---------------------------------------------------------------------------
// K3: per-row top-128 of |x*colsum| via 4-pass radix select, exact ties
// (lowest index first), write masked x as bf16. One 256-thread block per row.
// ---------------------------------------------------------------------------
__global__ __launch_bounds__(256) void topk_mask(const float* __restrict__ x,
                                                 const float* __restrict__ cs,
                                                 u16* __restrict__ xz) {
    __shared__ uint32_t hist[256];
    __shared__ uint32_t suf[256];
    __shared__ uint32_t s_scan[256];
    __shared__ uint32_t s_prefix, s_krem;

    const int b = blockIdx.x, t = threadIdx.x;
    const float4* xrow = (const float4*)(x + (size_t)b * IN_DIM);
    const float4* csv  = (const float4*)cs;

    float    xr[16];
    uint32_t ul[16];
#pragma unroll
    for (int q = 0; q < 4; ++q) {
        float4 xv = xrow[t * 4 + q];
        float4 cv = csv[t * 4 + q];
        xr[q*4+0] = xv.x; xr[q*4+1] = xv.y; xr[q*4+2] = xv.z; xr[q*4+3] = xv.w;
        ul[q*4+0] = __builtin_bit_cast(uint32_t, xv.x * cv.x) & 0x7fffffffu;
        ul[q*4+1] = __builtin_bit_cast(uint32_t, xv.y * cv.y) & 0x7fffffffu;
        ul[q*4+2] = __builtin_bit_cast(uint32_t, xv.z * cv.z) & 0x7fffffffu;
        ul[q*4+3] = __builtin_bit_cast(uint32_t, xv.w * cv.w) & 0x7fffffffu;
    }
    if (t == 0) { s_prefix = 0u; s_krem = K_SEL; }
    __syncthreads();

#pragma unroll
    for (int p = 3; p >= 0; --p) {
        const int sh = p * 8;
        const uint32_t hi_mask = (p == 3) ? 0u : (0xFFFFFFFFu << (sh + 8));
        const uint32_t prefix = s_prefix;
        const uint32_t krem   = s_krem;
        hist[t] = 0u;
        __syncthreads();
#pragma unroll
        for (int j = 0; j < 16; ++j) {
            uint32_t u = ul[j];
            if ((u & hi_mask) == (prefix & hi_mask))
                atomicAdd(&hist[(u >> sh) & 255u], 1u);
        }
        __syncthreads();
        uint32_t mine = hist[t];
        suf[t] = mine;
        __syncthreads();
#pragma unroll
        for (int off = 1; off < 256; off <<= 1) {
            uint32_t other = (t + off < 256) ? suf[t + off] : 0u;
            __syncthreads();
            mine += other;
            suf[t] = mine;
            __syncthreads();
        }
        uint32_t mysuf   = suf[t];
        uint32_t nextsuf = (t < 255) ? suf[t + 1] : 0u;
        if (mysuf >= krem && (t == 255 || nextsuf < krem)) {
            s_prefix = prefix | ((uint32_t)t << sh);
            s_krem   = krem - nextsuf;
        }
        __syncthreads();
    }
    const uint32_t T       = s_prefix;
    const uint32_t need_eq = s_krem;

    int cnt = 0;
#pragma unroll
    for (int j = 0; j < 16; ++j) cnt += (ul[j] == T) ? 1 : 0;
    s_scan[t] = (uint32_t)cnt;
    __syncthreads();
    uint32_t inc = (uint32_t)cnt;
#pragma unroll
    for (int off = 1; off < 256; off <<= 1) {
        uint32_t other = (t >= off) ? s_scan[t - off] : 0u;
        __syncthreads();
        inc += other;
        s_scan[t] = inc;
        __syncthreads();
    }
    const int base = (int)(inc - (uint32_t)cnt);

    union { u16 us[16]; uint4 v[2]; } ob;
    int eqseen = 0;
#pragma unroll
    for (int j = 0; j < 16; ++j) {
        uint32_t u = ul[j];
        bool drop = (u > T);
        if (u == T) {
            if (base + eqseen < (int)need_eq) drop = true;
            ++eqseen;
        }
        ob.us[j] = drop ? (u16)0 : f2bf(xr[j]);
    }
    uint4* dst = (uint4*)(xz + (size_t)b * IN_DIM + t * 16);
    dst[0] = ob.v[0];
    dst[1] = ob.v[1];
}

// ---------------------------------------------------------------------------
// K4: bf16 GEMM C = A @ B^T, 256x256 tile, BK=64, 8 waves (2Mx4N).
// r7 pipelined-frag schedule reduced to TWO barriers per tile:
//   P0 (qm0,ks0): rd a0k1,bk1; stage S4(k+1)=A-r1->bufN; mm(a0k0,bk0)
//   P1 (qm0,ks1): rd a1k0,a1k1; mm(a0k1,bk1);                [BARRIER: WAR]
//   P2 (qm1,ks0): stage S1(k+2)=A-r0 + S2(k+2)=B-r0 ->bufC; mm(a1k0,bk0);
//                 vmcnt(4) publish                           [BARRIER: RAW]
//   P3 (qm1,ks1): rd a0k0,bk0 (tile k+1, bufN); stage S3(k+2)=B-r1; mm(a1k1,bk1)
// WAR proof (no in-loop lgkm needed): a staged region's prior reads are
// consumed by an MFMA (compiler counted lgkm wait => reads complete) in a
// phase strictly before a retained barrier that precedes the stage:
//   S1/S2@P2(k): bufC A-r0/B-r0 reads consumed by P1(k)/P0(k) mm < P1-end bar
//   S3@P3(k):    bufC B-r1 (bk1) consumed by P1(k) mm < P2-end bar
//   S4@P0(k):    bufN A-r1 (a1k*) consumed by P2(k-1) mm < P2-end(k-1) bar
// RAW: vmcnt(4)@P2-end(k) drains in-order through S4(k+1) (keeps only
// S1,S2(k+2)) => tile k+1 fully resident; first reads at P3(k)/P0,P1(k+1).
// Tail: vmcnt(0) @ k>=NT-2. T2 XOR-swizzle (0 conflicts), T5 setprio.
// ---------------------------------------------------------------------------
#define NT 64

__global__ __launch_bounds__(512, 2) void gemm_pl(const u16* __restrict__ A,
                                                  const u16* __restrict__ Bm,
                                                  float* __restrict__ C) {
    __shared__ u16 lds_[65536];   // 128 KB

    const int bid = blockIdx.x;
    const int swz = (bid & 7) * 32 + (bid >> 3);   // 256 blocks, 8 XCDs
    const int m0 = (swz >> 4) * 256, n0 = (swz & 15) * 256;

    const int t = threadIdx.x;
    const int l = t & 63;
    const int lr = l & 15, lk = l >> 4;
    const int w = t >> 6;
    const int wm = w >> 2, wn = w & 3;

    const int cswz = ((t & 7) ^ ((t >> 3) & 7)) * 8;   // staging src col (elems)
    const int c0   = (lk ^ (lr & 7)) * 8;              // swizzled col, ks=0
    const int c1   = c0 ^ 32;                          // ks=1

    f32x4 acc[8][4];
#pragma unroll
    for (int i = 0; i < 8; ++i)
#pragma unroll
        for (int j = 0; j < 4; ++j) acc[i][j] = f32x4{0.f, 0.f, 0.f, 0.f};

#define GLOAD(g, off_bytes)                                                     \
    __builtin_amdgcn_global_load_lds(                                           \
        (const __attribute__((address_space(1))) void*)(g),                     \
        (__attribute__((address_space(3))) void*)(((char*)lds_) + (off_bytes)), \
        16, 0, 0)

    // A region r: rows {g*128 + r*64 .. +64} for g=0,1 -> 16KB
    auto stA = [&](int kb, int r, int kt) {
#pragma unroll
        for (int g = 0; g < 2; ++g)
            GLOAD(A + (size_t)(m0 + g * 128 + r * 64 + (t >> 3)) * IN_DIM + kt + cswz,
                  kb * 65536 + r * 16384 + g * 8192 + t * 16);
    };
    // B region r: rows {r*128 + g*64 .. +64} for g=0,1 -> 16KB
    auto stB = [&](int kb, int r, int kt) {
#pragma unroll
        for (int g = 0; g < 2; ++g)
            GLOAD(Bm + (size_t)(n0 + r * 128 + g * 64 + (t >> 3)) * IN_DIM + kt + cswz,
                  kb * 65536 + 32768 + r * 16384 + g * 8192 + t * 16);
    };

    // frag reads (elem offsets): A(qm,mi): bufo + qm*8192 + wm*4096 + lr*64
    //  + mi*1024 + c ; B(ni): bufo + 16384 + (wn>>1)*8192 + (wn&1)*4096
    //  + lr*64 + ni*1024 + c
    auto rdA = [&](bf16x8 (&dst)[4], int bufo, int qm, int c) {
#pragma unroll
        for (int mi = 0; mi < 4; ++mi)
            dst[mi] = *(const bf16x8*)&lds_[bufo + qm * 8192 + wm * 4096 + lr * 64 + mi * 1024 + c];
    };
    auto rdB = [&](bf16x8 (&dst)[4], int bufo, int c) {
#pragma unroll
        for (int ni = 0; ni < 4; ++ni)
            dst[ni] = *(const bf16x8*)&lds_[bufo + 16384 + (wn >> 1) * 8192 + (wn & 1) * 4096 + lr * 64 + ni * 1024 + c];
    };
    auto mm = [&](int base, bf16x8 (&Aa)[4], bf16x8 (&Bb)[4]) {
        __builtin_amdgcn_s_setprio(1);
#pragma unroll
        for (int mi = 0; mi < 4; ++mi)
#pragma unroll
            for (int ni = 0; ni < 4; ++ni)
                acc[base + mi][ni] = __builtin_amdgcn_mfma_f32_16x16x32_bf16(
                    Aa[mi], Bb[ni], acc[base + mi][ni], 0, 0, 0);
        __builtin_amdgcn_s_setprio(0);
        __builtin_amdgcn_sched_barrier(0);
    };

    bf16x8 a0k0[4], a0k1[4], a1k0[4], a1k1[4], bk0[4], bk1[4];

    // prologue: tile0 complete + S1,S2,S3(1); vmcnt(6) leaves exactly those 6;
    // publish tile0; pre-read P0's frags (loop-entry state = post-P3).
    stA(0, 0, 0); stA(0, 1, 0); stB(0, 0, 0); stB(0, 1, 0);
    stA(1, 0, 64); stB(1, 0, 64); stB(1, 1, 64);
    asm volatile("s_waitcnt vmcnt(6)" ::: "memory");
    __builtin_amdgcn_s_barrier();
    asm volatile("" ::: "memory");
    rdA(a0k0, 0, 0, c0);
    rdB(bk0, 0, c0);

    for (int k = 0; k < NT; ++k) {
        const int bufo = (k & 1) * 32768;               // elem offset
        const int bufno = bufo ^ 32768;
        const int kbC = k & 1, kbN = kbC ^ 1;
        const int kt1 = (k + 1) * 64, kt2 = (k + 2) * 64;

        // ---- P0 (qm0,ks0): reads a0k1,bk1(k); stage S4(k+1)=A-r1 -> bufN ----
        rdA(a0k1, bufo, 0, c1);
        rdB(bk1, bufo, c1);
        if (k < NT - 1) stA(kbN, 1, kt1);
        mm(0, a0k0, bk0);
        // (no barrier — WAR pairs covered by P1-end / P2-end barriers)

        // ---- P1 (qm0,ks1): reads a1k0,a1k1(k); WAR barrier ----
        rdA(a1k0, bufo, 1, c0);
        rdA(a1k1, bufo, 1, c1);
        mm(0, a0k1, bk1);
        asm volatile("" ::: "memory");
        __builtin_amdgcn_s_barrier();
        asm volatile("" ::: "memory");

        // ---- P2 (qm1,ks0): stage S1(k+2)=A-r0 + S2(k+2)=B-r0; publish ----
        if (k < NT - 2) { stA(kbC, 0, kt2); stB(kbC, 0, kt2); }
        mm(4, a1k0, bk0);
        if (k < NT - 2) {
            asm volatile("s_waitcnt vmcnt(4)" ::: "memory");
        } else {
            asm volatile("s_waitcnt vmcnt(0)" ::: "memory");
        }
        __builtin_amdgcn_s_barrier();
        asm volatile("" ::: "memory");

        // ---- P3 (qm1,ks1): reads a0k0,bk0(k+1) from bufN; stage S3(k+2) ----
        if (k < NT - 1) {
            rdA(a0k0, bufno, 0, c0);
            rdB(bk0, bufno, c0);
        }
        if (k < NT - 2) stB(kbC, 1, kt2);
        mm(4, a1k1, bk1);
        // (no barrier — next tile's P0 stage S4 covered by P2-end barrier)
    }
#undef GLOAD

    // epilogue: C/D layout col = lane&15, row = (lane>>4)*4 + r
#pragma unroll
    for (int gmi = 0; gmi < 8; ++gmi)
#pragma unroll
        for (int ni = 0; ni < 4; ++ni)
#pragma unroll
            for (int r = 0; r < 4; ++r) {
                int row = m0 + wm * 128 + (gmi >> 2) * 64 + (gmi & 3) * 16 + lk * 4 + r;
                int col = n0 + wn * 64 + ni * 16 + lr;
                C[(size_t)row * OUT_DIM + col] = acc[gmi][ni][r];
            }
}

// ---------------------------------------------------------------------------
extern "C" void kernel_launch(void* const* d_in, const int* in_sizes, int n_in,
                              void* d_out, int out_size, void* d_ws, size_t ws_size,
                              hipStream_t stream) {
    const float* x = (const float*)d_in[0];
    const float* W = (const float*)d_in[1];
    float* out = (float*)d_out;

    char* ws = (char*)d_ws;
    u16*    Wb   = (u16*)ws;                                   // 32 MB bf16 W
    u16*    xz   = (u16*)(ws + (size_t)32 * 1024 * 1024);      // 32 MB bf16 masked x
    float*  cs   = (float*)(ws + (size_t)64 * 1024 * 1024);    // 16 KB colsum
    double* part = (double*)d_out;  // 4 MB partials, consumed before gemm writes

    colsum_conv<<<512, 256, 0, stream>>>(W, part, Wb);
    colsum_final<<<256, 256, 0, stream>>>(part, cs);
    topk_mask<<<4096, 256, 0, stream>>>(x, cs, xz);
    gemm_pl<<<256, 512, 0, stream>>>(xz, Wb, out);
}

// Round 11
// 178.270 us; speedup vs baseline: 1.0596x; 1.0132x over previous
//
#include <hip/hip_runtime.h>
#include <hip/hip_bf16.h>
#include <stdint.h>

#define B_DIM   4096
#define IN_DIM  4096
#define OUT_DIM 4096
#define K_SEL   128

typedef unsigned short u16;
typedef __bf16 bf16x8 __attribute__((ext_vector_type(8)));
typedef float  f32x4  __attribute__((ext_vector_type(4)));

static __device__ __forceinline__ u16 f2bf(float f) {
    uint32_t u = __builtin_bit_cast(uint32_t, f);
    uint32_t r = (u + 0x7fffu + ((u >> 16) & 1u)) >> 16;
    return (u16)r;
}

// ---------------------------------------------------------------------------
// K1: column sums of W (fp64 partials over 32-row chunks) + W -> bf16.
// 512 blocks; float4 loads. part = [128][4096] doubles (4MB) in d_out.
// ---------------------------------------------------------------------------
__global__ __launch_bounds__(256) void colsum_conv(const float* __restrict__ W,
                                                   double* __restrict__ part,
                                                   u16* __restrict__ Wb) {
    int cb = blockIdx.x & 3;
    int rb = blockIdx.x >> 2;          // 0..127
    int c4 = cb * 256 + threadIdx.x;   // float4 index within a row
    int row0 = rb * 32;
    double s0 = 0.0, s1 = 0.0, s2 = 0.0, s3 = 0.0;
    for (int r = 0; r < 32; ++r) {
        const float4 v = ((const float4*)(W + (size_t)(row0 + r) * IN_DIM))[c4];
        s0 += (double)v.x; s1 += (double)v.y; s2 += (double)v.z; s3 += (double)v.w;
        ushort4 o;
        o.x = f2bf(v.x); o.y = f2bf(v.y); o.z = f2bf(v.z); o.w = f2bf(v.w);
        ((ushort4*)(Wb + (size_t)(row0 + r) * IN_DIM))[c4] = o;
    }
    double4 d; d.x = s0; d.y = s1; d.z = s2; d.w = s3;
    ((double4*)(part + (size_t)rb * IN_DIM))[c4] = d;
}

// 256 blocks x 256 threads: block handles 16 cols; 16 row-groups of 8.
__global__ __launch_bounds__(256) void colsum_final(const double* __restrict__ part,
                                                    float* __restrict__ cs) {
    __shared__ double red[256];
    const int t = threadIdx.x;
    const int c = blockIdx.x * 16 + (t & 15);
    const int g = t >> 4;              // 0..15
    double s = 0.0;
    for (int r = 0; r < 8; ++r) s += part[(size_t)(g * 8 + r) * IN_DIM + c];
    red[t] = s;
    __syncthreads();
    for (int off = 128; off >= 16; off >>= 1) {
        if (t < off) red[t] += red[t + off];
        __syncthreads();
    }
    if (t < 16) cs[blockIdx.x * 16 + t] = (float)red[t];
}

// ---------------------------------------------------------------------------
// K3: per-row top-128 of |x*colsum| via 4-pass radix select, exact ties
// (lowest index first), masked x as bf16. One 256-thread block per row.
// Wave-level shfl scans: ~19 barriers/block (was ~70).
// ---------------------------------------------------------------------------
__global__ __launch_bounds__(256) void topk_mask(const float* __restrict__ x,
                                                 const float* __restrict__ cs,
                                                 u16* __restrict__ xz) {
    __shared__ uint32_t hist[256];
    __shared__ uint32_t wtot[4];
    __shared__ uint32_t s_prefix, s_krem;

    const int b = blockIdx.x, t = threadIdx.x;
    const int lane = t & 63, wv = t >> 6;
    const float4* xrow = (const float4*)(x + (size_t)b * IN_DIM);
    const float4* csv  = (const float4*)cs;

    float    xr[16];
    uint32_t ul[16];
#pragma unroll
    for (int q = 0; q < 4; ++q) {
        float4 xv = xrow[t * 4 + q];
        float4 cv = csv[t * 4 + q];
        xr[q*4+0] = xv.x; xr[q*4+1] = xv.y; xr[q*4+2] = xv.z; xr[q*4+3] = xv.w;
        ul[q*4+0] = __builtin_bit_cast(uint32_t, xv.x * cv.x) & 0x7fffffffu;
        ul[q*4+1] = __builtin_bit_cast(uint32_t, xv.y * cv.y) & 0x7fffffffu;
        ul[q*4+2] = __builtin_bit_cast(uint32_t, xv.z * cv.z) & 0x7fffffffu;
        ul[q*4+3] = __builtin_bit_cast(uint32_t, xv.w * cv.w) & 0x7fffffffu;
    }
    if (t == 0) { s_prefix = 0u; s_krem = K_SEL; }
    __syncthreads();

#pragma unroll
    for (int p = 3; p >= 0; --p) {
        const int sh = p * 8;
        const uint32_t hi_mask = (p == 3) ? 0u : (0xFFFFFFFFu << (sh + 8));
        const uint32_t prefix = s_prefix;
        const uint32_t krem   = s_krem;
        hist[t] = 0u;
        __syncthreads();                      // zero visible before atomics
#pragma unroll
        for (int j = 0; j < 16; ++j) {
            uint32_t u = ul[j];
            if ((u & hi_mask) == (prefix & hi_mask))
                atomicAdd(&hist[(u >> sh) & 255u], 1u);
        }
        __syncthreads();                      // atomics done
        const uint32_t h = hist[t];
        // suffix sum within wave's 64 bins (no barriers)
        uint32_t v = h;
#pragma unroll
        for (int off = 1; off < 64; off <<= 1) {
            uint32_t got = __shfl_down(v, off);
            if (lane + off < 64) v += got;
        }
        if (lane == 0) wtot[wv] = v;          // wave-total = suffix at lane 0
        __syncthreads();                      // wave totals ready
        uint32_t add = 0;
#pragma unroll
        for (int ww = 0; ww < 4; ++ww)
            if (ww > wv) add += wtot[ww];
        const uint32_t mysuf   = v + add;     // global suffix at bin t
        const uint32_t nextsuf = mysuf - h;   // global suffix at bin t+1
        if (mysuf >= krem && nextsuf < krem) {
            s_prefix = prefix | ((uint32_t)t << sh);
            s_krem   = krem - nextsuf;
        }
        __syncthreads();                      // selection published
    }
    const uint32_t T       = s_prefix;
    const uint32_t need_eq = s_krem;

    // stable enumeration of ==T elements: inclusive prefix scan of counts
    uint32_t cnt = 0;
#pragma unroll
    for (int j = 0; j < 16; ++j) cnt += (ul[j] == T) ? 1u : 0u;
    uint32_t inc = cnt;
#pragma unroll
    for (int off = 1; off < 64; off <<= 1) {
        uint32_t got = __shfl_up(inc, off);
        if (lane >= off) inc += got;
    }
    if (lane == 63) wtot[wv] = inc;           // wave total (inclusive @ lane63)
    __syncthreads();
    uint32_t wbase = 0;
#pragma unroll
    for (int ww = 0; ww < 4; ++ww)
        if (ww < wv) wbase += wtot[ww];
    const int base = (int)(inc + wbase - cnt);

    union { u16 us[16]; uint4 v4[2]; } ob;
    int eqseen = 0;
#pragma unroll
    for (int j = 0; j < 16; ++j) {
        uint32_t u = ul[j];
        bool drop = (u > T);
        if (u == T) {
            if (base + eqseen < (int)need_eq) drop = true;
            ++eqseen;
        }
        ob.us[j] = drop ? (u16)0 : f2bf(xr[j]);
    }
    uint4* dst = (uint4*)(xz + (size_t)b * IN_DIM + t * 16);
    dst[0] = ob.v4[0];
    dst[1] = ob.v4[1];
}

// ---------------------------------------------------------------------------
// K4: bf16 GEMM C = A @ B^T, 256x256 tile, BK=64, 8 waves (2Mx4N).
// Pipelined frags, TWO barriers per tile (r10 structure, unchanged):
//   P0: rd a0k1,bk1; stage S4(k+1)=A-r1->bufN; mm(a0k0,bk0)
//   P1: rd a1k0,a1k1; mm(a0k1,bk1);                [BARRIER: WAR]
//   P2: stage S1(k+2)=A-r0 + S2(k+2)=B-r0; mm(a1k0,bk0); vmcnt(4) [BARRIER]
//   P3: rd a0k0,bk0 (k+1, bufN); stage S3(k+2)=B-r1; mm(a1k1,bk1)
// WAR/RAW ledger as r10. T2 XOR-swizzle (0 conflicts), T5 setprio.
// ---------------------------------------------------------------------------
#define NT 64

__global__ __launch_bounds__(512, 2) void gemm_pl(const u16* __restrict__ A,
                                                  const u16* __restrict__ Bm,
                                                  float* __restrict__ C) {
    __shared__ u16 lds_[65536];   // 128 KB

    const int bid = blockIdx.x;
    const int swz = (bid & 7) * 32 + (bid >> 3);   // 256 blocks, 8 XCDs
    const int m0 = (swz >> 4) * 256, n0 = (swz & 15) * 256;

    const int t = threadIdx.x;
    const int l = t & 63;
    const int lr = l & 15, lk = l >> 4;
    const int w = t >> 6;
    const int wm = w >> 2, wn = w & 3;

    const int cswz = ((t & 7) ^ ((t >> 3) & 7)) * 8;   // staging src col (elems)
    const int c0   = (lk ^ (lr & 7)) * 8;              // swizzled col, ks=0
    const int c1   = c0 ^ 32;                          // ks=1

    f32x4 acc[8][4];
#pragma unroll
    for (int i = 0; i < 8; ++i)
#pragma unroll
        for (int j = 0; j < 4; ++j) acc[i][j] = f32x4{0.f, 0.f, 0.f, 0.f};

#define GLOAD(g, off_bytes)                                                     \
    __builtin_amdgcn_global_load_lds(                                           \
        (const __attribute__((address_space(1))) void*)(g),                     \
        (__attribute__((address_space(3))) void*)(((char*)lds_) + (off_bytes)), \
        16, 0, 0)

    auto stA = [&](int kb, int r, int kt) {
#pragma unroll
        for (int g = 0; g < 2; ++g)
            GLOAD(A + (size_t)(m0 + g * 128 + r * 64 + (t >> 3)) * IN_DIM + kt + cswz,
                  kb * 65536 + r * 16384 + g * 8192 + t * 16);
    };
    auto stB = [&](int kb, int r, int kt) {
#pragma unroll
        for (int g = 0; g < 2; ++g)
            GLOAD(Bm + (size_t)(n0 + r * 128 + g * 64 + (t >> 3)) * IN_DIM + kt + cswz,
                  kb * 65536 + 32768 + r * 16384 + g * 8192 + t * 16);
    };

    auto rdA = [&](bf16x8 (&dst)[4], int bufo, int qm, int c) {
#pragma unroll
        for (int mi = 0; mi < 4; ++mi)
            dst[mi] = *(const bf16x8*)&lds_[bufo + qm * 8192 + wm * 4096 + lr * 64 + mi * 1024 + c];
    };
    auto rdB = [&](bf16x8 (&dst)[4], int bufo, int c) {
#pragma unroll
        for (int ni = 0; ni < 4; ++ni)
            dst[ni] = *(const bf16x8*)&lds_[bufo + 16384 + (wn >> 1) * 8192 + (wn & 1) * 4096 + lr * 64 + ni * 1024 + c];
    };
    auto mm = [&](int base, bf16x8 (&Aa)[4], bf16x8 (&Bb)[4]) {
        __builtin_amdgcn_s_setprio(1);
#pragma unroll
        for (int mi = 0; mi < 4; ++mi)
#pragma unroll
            for (int ni = 0; ni < 4; ++ni)
                acc[base + mi][ni] = __builtin_amdgcn_mfma_f32_16x16x32_bf16(
                    Aa[mi], Bb[ni], acc[base + mi][ni], 0, 0, 0);
        __builtin_amdgcn_s_setprio(0);
        __builtin_amdgcn_sched_barrier(0);
    };

    bf16x8 a0k0[4], a0k1[4], a1k0[4], a1k1[4], bk0[4], bk1[4];

    stA(0, 0, 0); stA(0, 1, 0); stB(0, 0, 0); stB(0, 1, 0);
    stA(1, 0, 64); stB(1, 0, 64); stB(1, 1, 64);
    asm volatile("s_waitcnt vmcnt(6)" ::: "memory");
    __builtin_amdgcn_s_barrier();
    asm volatile("" ::: "memory");
    rdA(a0k0, 0, 0, c0);
    rdB(bk0, 0, c0);

    for (int k = 0; k < NT; ++k) {
        const int bufo = (k & 1) * 32768;               // elem offset
        const int bufno = bufo ^ 32768;
        const int kbC = k & 1, kbN = kbC ^ 1;
        const int kt1 = (k + 1) * 64, kt2 = (k + 2) * 64;

        // ---- P0: reads a0k1,bk1(k); stage S4(k+1)=A-r1 -> bufN ----
        rdA(a0k1, bufo, 0, c1);
        rdB(bk1, bufo, c1);
        if (k < NT - 1) stA(kbN, 1, kt1);
        mm(0, a0k0, bk0);

        // ---- P1: reads a1k0,a1k1(k); WAR barrier ----
        rdA(a1k0, bufo, 1, c0);
        rdA(a1k1, bufo, 1, c1);
        mm(0, a0k1, bk1);
        asm volatile("" ::: "memory");
        __builtin_amdgcn_s_barrier();
        asm volatile("" ::: "memory");

        // ---- P2: stage S1(k+2)=A-r0 + S2(k+2)=B-r0; publish ----
        if (k < NT - 2) { stA(kbC, 0, kt2); stB(kbC, 0, kt2); }
        mm(4, a1k0, bk0);
        if (k < NT - 2) {
            asm volatile("s_waitcnt vmcnt(4)" ::: "memory");
        } else {
            asm volatile("s_waitcnt vmcnt(0)" ::: "memory");
        }
        __builtin_amdgcn_s_barrier();
        asm volatile("" ::: "memory");

        // ---- P3: reads a0k0,bk0(k+1) from bufN; stage S3(k+2)=B-r1 ----
        if (k < NT - 1) {
            rdA(a0k0, bufno, 0, c0);
            rdB(bk0, bufno, c0);
        }
        if (k < NT - 2) stB(kbC, 1, kt2);
        mm(4, a1k1, bk1);
    }
#undef GLOAD

    // epilogue: C/D layout col = lane&15, row = (lane>>4)*4 + r
#pragma unroll
    for (int gmi = 0; gmi < 8; ++gmi)
#pragma unroll
        for (int ni = 0; ni < 4; ++ni)
#pragma unroll
            for (int r = 0; r < 4; ++r) {
                int row = m0 + wm * 128 + (gmi >> 2) * 64 + (gmi & 3) * 16 + lk * 4 + r;
                int col = n0 + wn * 64 + ni * 16 + lr;
                C[(size_t)row * OUT_DIM + col] = acc[gmi][ni][r];
            }
}

// ---------------------------------------------------------------------------
extern "C" void kernel_launch(void* const* d_in, const int* in_sizes, int n_in,
                              void* d_out, int out_size, void* d_ws, size_t ws_size,
                              hipStream_t stream) {
    const float* x = (const float*)d_in[0];
    const float* W = (const float*)d_in[1];
    float* out = (float*)d_out;

    char* ws = (char*)d_ws;
    u16*    Wb   = (u16*)ws;                                   // 32 MB bf16 W
    u16*    xz   = (u16*)(ws + (size_t)32 * 1024 * 1024);      // 32 MB bf16 masked x
    float*  cs   = (float*)(ws + (size_t)64 * 1024 * 1024);    // 16 KB colsum
    double* part = (double*)d_out;  // 4 MB partials, consumed before gemm writes

    colsum_conv<<<512, 256, 0, stream>>>(W, part, Wb);
    colsum_final<<<256, 256, 0, stream>>>(part, cs);
    topk_mask<<<4096, 256, 0, stream>>>(x, cs, xz);
    gemm_pl<<<256, 512, 0, stream>>>(xz, Wb, out);
}